// Round 1
// baseline (735.016 us; speedup 1.0000x reference)
//
#include <hip/hip_runtime.h>
#include <hip/hip_bf16.h>
#include <math.h>

// ---------- types ----------
typedef __attribute__((ext_vector_type(8))) short bf16x8;
typedef __attribute__((ext_vector_type(4))) float f32x4;

#define MFMA16(a, b, c) __builtin_amdgcn_mfma_f32_16x16x32_bf16((a), (b), (c), 0, 0, 0)

static __device__ __forceinline__ unsigned short f2bf(float f) {
  __hip_bfloat16 h = __float2bfloat16(f);
  unsigned short u;
  __builtin_memcpy(&u, &h, 2);
  return u;
}
static __device__ __forceinline__ float bf2f(unsigned short u) {
  unsigned int x = ((unsigned int)u) << 16;
  float f;
  __builtin_memcpy(&f, &x, 4);
  return f;
}

// ---------- cast fp32 -> bf16 (vectorized) ----------
__global__ void cast_f32_bf16(const float* __restrict__ src, unsigned short* __restrict__ dst, int n) {
  int i = (blockIdx.x * 256 + threadIdx.x) * 8;
  if (i >= n) return;
  float4 a = *(const float4*)(src + i);
  float4 b = *(const float4*)(src + i + 4);
  union { unsigned short u[8]; bf16x8 v; } o;
  o.u[0] = f2bf(a.x); o.u[1] = f2bf(a.y); o.u[2] = f2bf(a.z); o.u[3] = f2bf(a.w);
  o.u[4] = f2bf(b.x); o.u[5] = f2bf(b.y); o.u[6] = f2bf(b.z); o.u[7] = f2bf(b.w);
  *(bf16x8*)(dst + i) = o.v;
}

// ---------- Wsmall = [Wkv(256) ; Wkvh(32) ; zeros(96)]  (384 x 2048, bf16) ----------
__global__ void build_wsmall(const float* __restrict__ Wkv, const float* __restrict__ Wkvh,
                             unsigned short* __restrict__ dst) {
  int row = blockIdx.x;           // 0..383
  int c = threadIdx.x * 8;        // 0..2040
  const float* src = nullptr;
  if (row < 256) src = Wkv + (size_t)row * 2048;
  else if (row < 288) src = Wkvh + (size_t)(row - 256) * 2048;
  union { unsigned short u[8]; bf16x8 v; } o;
  if (src) {
    float4 a = *(const float4*)(src + c);
    float4 b = *(const float4*)(src + c + 4);
    o.u[0] = f2bf(a.x); o.u[1] = f2bf(a.y); o.u[2] = f2bf(a.z); o.u[3] = f2bf(a.w);
    o.u[4] = f2bf(b.x); o.u[5] = f2bf(b.y); o.u[6] = f2bf(b.z); o.u[7] = f2bf(b.w);
  } else {
    for (int j = 0; j < 8; j++) o.u[j] = 0;
  }
  *(bf16x8*)(dst + (size_t)row * 2048 + c) = o.v;
}

// ---------- rope cos/sin table: (n, f) f<64 ----------
__global__ void rope_table(float2* __restrict__ cs) {
  int i = blockIdx.x * 256 + threadIdx.x;  // 2048*64
  int f = i & 63, n = i >> 6;
  float inv = powf(10000.0f, -(float)(2 * f) / 128.0f);
  float ang = (float)n * inv;
  cs[i] = make_float2(cosf(ang), sinf(ang));
}

// ---------- g = x @ Wg^T in fp32 (precision-critical) ----------
__global__ __launch_bounds__(256) void gproj(const float* __restrict__ x, const float* __restrict__ Wg,
                                             float* __restrict__ g) {
  int tid = blockIdx.x * 256 + threadIdx.x;  // 4096*32
  int tok = tid >> 5, oc = tid & 31;
  const float* xr = x + (size_t)tok * 2048;
  const float* wr = Wg + (size_t)oc * 2048;
  float acc = 0.f;
  for (int k = 0; k < 2048; k += 4) {
    float4 a = *(const float4*)(xr + k);
    float4 w = *(const float4*)(wr + k);
    acc += a.x * w.x + a.y * w.y + a.z * w.z + a.w * w.w;
  }
  g[(size_t)tok * 32 + oc] = acc;
}

// ---------- gated double cumsum scan, per (b, ch) ----------
__global__ __launch_bounds__(256) void scan_kernel(const float* __restrict__ g,
                                                   const float* __restrict__ small_out,
                                                   float* __restrict__ khvh) {
  int b = blockIdx.x >> 5, ch = blockIdx.x & 31;
  int t = threadIdx.x;
  __shared__ float part[256];
  int base_tok = b * 2048;
  // phase A: exclusive scan of log_sigmoid(g)
  float lsg[8];
  float run = 0.f;
#pragma unroll
  for (int j = 0; j < 8; j++) {
    int n = t * 8 + j;
    float gv = g[(size_t)(base_tok + n) * 32 + ch];
    float ls = (gv >= 0.f) ? -log1pf(expf(-gv)) : gv - log1pf(expf(gv));
    run += ls;
    lsg[j] = run;  // inclusive local
  }
  part[t] = run;
  __syncthreads();
  for (int off = 1; off < 256; off <<= 1) {
    float v = (t >= off) ? part[t - off] : 0.f;
    __syncthreads();
    part[t] += v;
    __syncthreads();
  }
  float base = (t > 0) ? part[t - 1] : 0.f;
  __syncthreads();
  // phase B: inclusive scan of kvh * exp(lfc)
  float term[8];
  float run2 = 0.f;
#pragma unroll
  for (int j = 0; j < 8; j++) {
    int n = t * 8 + j;
    float kvh = small_out[(size_t)(base_tok + n) * 384 + 256 + ch];
    float lf = base + (j > 0 ? lsg[j - 1] : 0.f);  // exclusive prefix
    run2 += kvh * expf(lf);
    term[j] = run2;
  }
  part[t] = run2;
  __syncthreads();
  for (int off = 1; off < 256; off <<= 1) {
    float v = (t >= off) ? part[t - off] : 0.f;
    __syncthreads();
    part[t] += v;
    __syncthreads();
  }
  float base2 = (t > 0) ? part[t - 1] : 0.f;
#pragma unroll
  for (int j = 0; j < 8; j++) {
    int n = t * 8 + j;
    khvh[(size_t)(base_tok + n) * 32 + ch] = base2 + term[j];
  }
}

// ---------- rope q in place, q_r layout (b,h,n,d) ----------
__global__ void rope_q(unsigned short* __restrict__ q_r, const float2* __restrict__ cs) {
  int i = blockIdx.x * 256 + threadIdx.x;  // 32*2048*64
  int f = i & 63;
  int n = (i >> 6) & 2047;
  int bh = i >> 17;
  unsigned short* p = q_r + ((size_t)bh * 2048 + n) * 128;
  float t1 = bf2f(p[f]), t2 = bf2f(p[f + 64]);
  float2 c = cs[(n << 6) + f];
  p[f] = f2bf(t1 * c.x - t2 * c.y);
  p[f + 64] = f2bf(t2 * c.x + t1 * c.y);
}

// ---------- build k_r, v_r (b,h,n,d) = rope(kp)*kh , vp*vh ----------
__global__ __launch_bounds__(256) void build_kv(const float* __restrict__ small_out,
                                                const float* __restrict__ khvh,
                                                const float2* __restrict__ cs,
                                                unsigned short* __restrict__ k_r,
                                                unsigned short* __restrict__ v_r) {
  int tok = blockIdx.x;
  int b = tok >> 11, n = tok & 2047;
  __shared__ float kpr[128], vps[128], khs[16], vhs[16];
  int t = threadIdx.x;
  const float* so = small_out + (size_t)tok * 384;
  if (t < 64) {
    float k1 = so[t], k2 = so[t + 64];
    float2 c = cs[(n << 6) + t];
    kpr[t] = k1 * c.x - k2 * c.y;
    kpr[t + 64] = k2 * c.x + k1 * c.y;
  } else if (t < 192) {
    int d = t - 64;
    vps[d] = so[128 + d];
  } else if (t < 224) {
    int ch = t - 192;
    float v = khvh[(size_t)tok * 32 + ch];
    if (ch < 16) khs[ch] = v; else vhs[ch - 16] = v;
  }
  __syncthreads();
#pragma unroll
  for (int i = 0; i < 8; i++) {
    int idx = i * 256 + t;
    int h = idx >> 7, d = idx & 127;
    size_t o = (((size_t)b * 16 + h) * 2048 + n) * 128 + d;
    k_r[o] = f2bf(kpr[d] * khs[h]);
    v_r[o] = f2bf(vps[d] * vhs[h]);
  }
}

// ---------- m97-style NT GEMM: C(MxN) = A(MxK) @ B(NxK)^T, bf16 in, fp32 acc ----------
// MODE 0: C fp32 row-major (ldc).  MODE 2: scatter bf16 to q_r layout (b,h,n,d).
template <int MODE>
__global__ __launch_bounds__(256) void gemm_bt(const unsigned short* __restrict__ A,
                                               const unsigned short* __restrict__ B,
                                               float* __restrict__ Cf,
                                               unsigned short* __restrict__ Cb,
                                               int K, int ldc) {
  __shared__ unsigned short As[128 * 32];
  __shared__ unsigned short Bs[128 * 32];
  int tid = threadIdx.x;
  int wave = tid >> 6, lane = tid & 63, l15 = lane & 15, lg = lane >> 4;
  int wr = wave >> 1, wc = wave & 1;
  int row0 = blockIdx.y * 128, col0 = blockIdx.x * 128;
  f32x4 acc[4][4];
#pragma unroll
  for (int m = 0; m < 4; m++)
#pragma unroll
    for (int n = 0; n < 4; n++) acc[m][n] = (f32x4){0.f, 0.f, 0.f, 0.f};

  for (int k0 = 0; k0 < K; k0 += 32) {
#pragma unroll
    for (int c = 0; c < 2; c++) {
      int chunk = c * 256 + tid;           // 0..511 chunks of 16B
      int r = chunk >> 2, kk = (chunk & 3) * 8;
      __builtin_amdgcn_global_load_lds(
          (const __attribute__((address_space(1))) void*)(A + (size_t)(row0 + r) * K + k0 + kk),
          (__attribute__((address_space(3))) void*)(As + ((size_t)c * 256 + wave * 64) * 8), 16, 0, 0);
      __builtin_amdgcn_global_load_lds(
          (const __attribute__((address_space(1))) void*)(B + (size_t)(col0 + r) * K + k0 + kk),
          (__attribute__((address_space(3))) void*)(Bs + ((size_t)c * 256 + wave * 64) * 8), 16, 0, 0);
    }
    __syncthreads();
    bf16x8 af[4], bfr[4];
#pragma unroll
    for (int m = 0; m < 4; m++) af[m] = *(const bf16x8*)&As[(wr * 64 + m * 16 + l15) * 32 + lg * 8];
#pragma unroll
    for (int n = 0; n < 4; n++) bfr[n] = *(const bf16x8*)&Bs[(wc * 64 + n * 16 + l15) * 32 + lg * 8];
#pragma unroll
    for (int m = 0; m < 4; m++)
#pragma unroll
      for (int n = 0; n < 4; n++) acc[m][n] = MFMA16(af[m], bfr[n], acc[m][n]);
    __syncthreads();
  }
  // epilogue: C/D layout col = lane&15, row = (lane>>4)*4 + reg
#pragma unroll
  for (int m = 0; m < 4; m++) {
    int row_b = row0 + wr * 64 + m * 16 + lg * 4;
#pragma unroll
    for (int n = 0; n < 4; n++) {
      int col = col0 + wc * 64 + n * 16 + l15;
#pragma unroll
      for (int j = 0; j < 4; j++) {
        int row = row_b + j;
        if (MODE == 0) {
          Cf[(size_t)row * ldc + col] = acc[m][n][j];
        } else {
          int b = row >> 11, nn = row & 2047, h = col >> 7, d = col & 127;
          Cb[(((size_t)b * 16 + h) * 2048 + nn) * 128 + d] = f2bf(acc[m][n][j]);
        }
      }
    }
  }
}

// ---------- flash attention: causal, per (b,h), Q tile 64, KV tile 64 ----------
__global__ __launch_bounds__(256) void flash_attn(const unsigned short* __restrict__ q_r,
                                                  const unsigned short* __restrict__ k_r,
                                                  const unsigned short* __restrict__ v_r,
                                                  unsigned short* __restrict__ o) {
  int qt = blockIdx.x, bh = blockIdx.y;
  const unsigned short* Qg = q_r + ((size_t)bh * 2048 + qt * 64) * 128;
  const unsigned short* Kg = k_r + (size_t)bh * 2048 * 128;
  const unsigned short* Vg = v_r + (size_t)bh * 2048 * 128;
  __shared__ unsigned short Qs[64 * 136];   // padded stride
  __shared__ unsigned short Ks[64 * 136];
  __shared__ unsigned short VTs[128 * 72];  // V transposed [d][kv], padded
  __shared__ unsigned short Ps[4][16 * 72];
  int tid = threadIdx.x, wave = tid >> 6, lane = tid & 63, l15 = lane & 15, lg = lane >> 4;

#pragma unroll
  for (int c = 0; c < 4; c++) {
    int e = (c * 256 + tid) * 8;
    int r = e >> 7, d0 = e & 127;
    *(bf16x8*)&Qs[r * 136 + d0] = *(const bf16x8*)(Qg + r * 128 + d0);
  }
  __syncthreads();
  bf16x8 qf[4];
#pragma unroll
  for (int kk = 0; kk < 4; kk++)
    qf[kk] = *(const bf16x8*)&Qs[(wave * 16 + l15) * 136 + kk * 32 + lg * 8];

  float m_r[4], l_r[4];
  f32x4 oacc[8];
#pragma unroll
  for (int j = 0; j < 4; j++) { m_r[j] = -INFINITY; l_r[j] = 0.f; }
#pragma unroll
  for (int db = 0; db < 8; db++) oacc[db] = (f32x4){0.f, 0.f, 0.f, 0.f};

  int qrow0 = qt * 64 + wave * 16 + lg * 4;
  const float scale = 0.08838834764831845f;  // 1/sqrt(128)

  for (int kt = 0; kt <= qt; ++kt) {
#pragma unroll
    for (int c = 0; c < 4; c++) {
      int e = (c * 256 + tid) * 8;
      int r = e >> 7, d0 = e & 127;
      *(bf16x8*)&Ks[r * 136 + d0] = *(const bf16x8*)(Kg + (size_t)(kt * 64 + r) * 128 + d0);
      bf16x8 vv = *(const bf16x8*)(Vg + (size_t)(kt * 64 + r) * 128 + d0);
#pragma unroll
      for (int j = 0; j < 8; j++) VTs[(d0 + j) * 72 + r] = ((unsigned short*)&vv)[j];
    }
    __syncthreads();

    f32x4 s[4];
#pragma unroll
    for (int cb = 0; cb < 4; cb++) s[cb] = (f32x4){0.f, 0.f, 0.f, 0.f};
#pragma unroll
    for (int kk = 0; kk < 4; kk++) {
#pragma unroll
      for (int cb = 0; cb < 4; cb++) {
        bf16x8 kf = *(const bf16x8*)&Ks[(cb * 16 + l15) * 136 + kk * 32 + lg * 8];
        s[cb] = MFMA16(qf[kk], kf, s[cb]);
      }
    }
    // scale + causal mask + row max
    float pm[4] = {-INFINITY, -INFINITY, -INFINITY, -INFINITY};
#pragma unroll
    for (int cb = 0; cb < 4; cb++) {
      int col = kt * 64 + cb * 16 + l15;
#pragma unroll
      for (int j = 0; j < 4; j++) {
        float v = s[cb][j] * scale;
        if (col > qrow0 + j) v = -INFINITY;
        s[cb][j] = v;
        pm[j] = fmaxf(pm[j], v);
      }
    }
#pragma unroll
    for (int off = 1; off < 16; off <<= 1) {
#pragma unroll
      for (int j = 0; j < 4; j++) pm[j] = fmaxf(pm[j], __shfl_xor(pm[j], off));
    }
    float corr[4], rs[4];
#pragma unroll
    for (int j = 0; j < 4; j++) {
      float mn = fmaxf(m_r[j], pm[j]);
      corr[j] = __expf(m_r[j] - mn);
      m_r[j] = mn;
      rs[j] = 0.f;
    }
    float p[4][4];
#pragma unroll
    for (int cb = 0; cb < 4; cb++)
#pragma unroll
      for (int j = 0; j < 4; j++) {
        float pv = __expf(s[cb][j] - m_r[j]);
        p[cb][j] = pv;
        rs[j] += pv;
      }
#pragma unroll
    for (int off = 1; off < 16; off <<= 1) {
#pragma unroll
      for (int j = 0; j < 4; j++) rs[j] += __shfl_xor(rs[j], off);
    }
#pragma unroll
    for (int j = 0; j < 4; j++) l_r[j] = l_r[j] * corr[j] + rs[j];
#pragma unroll
    for (int db = 0; db < 8; db++) {
      f32x4 t = oacc[db];
#pragma unroll
      for (int j = 0; j < 4; j++) t[j] *= corr[j];
      oacc[db] = t;
    }
    // P -> LDS (bf16), then PV
#pragma unroll
    for (int cb = 0; cb < 4; cb++)
#pragma unroll
      for (int j = 0; j < 4; j++) Ps[wave][(lg * 4 + j) * 72 + cb * 16 + l15] = f2bf(p[cb][j]);
    __syncthreads();
#pragma unroll
    for (int kc = 0; kc < 2; kc++) {
      bf16x8 pa = *(const bf16x8*)&Ps[wave][l15 * 72 + kc * 32 + lg * 8];
#pragma unroll
      for (int db = 0; db < 8; db++) {
        bf16x8 vb = *(const bf16x8*)&VTs[(db * 16 + l15) * 72 + kc * 32 + lg * 8];
        oacc[db] = MFMA16(pa, vb, oacc[db]);
      }
    }
    __syncthreads();
  }
  // epilogue -> o (tok, h*128+d) bf16
  int b = bh >> 4, h = bh & 15;
#pragma unroll
  for (int db = 0; db < 8; db++) {
    int d = db * 16 + l15;
#pragma unroll
    for (int j = 0; j < 4; j++) {
      int row = qrow0 + j;
      float val = oacc[db][j] / l_r[j];
      o[((size_t)(b * 2048 + row)) * 2048 + h * 128 + d] = f2bf(val);
    }
  }
}

// ---------- host launch ----------
extern "C" void kernel_launch(void* const* d_in, const int* in_sizes, int n_in,
                              void* d_out, int out_size, void* d_ws, size_t ws_size,
                              hipStream_t stream) {
  (void)in_sizes; (void)n_in; (void)out_size; (void)ws_size;
  const float* x    = (const float*)d_in[0];
  const float* Wq   = (const float*)d_in[1];
  const float* Wkv  = (const float*)d_in[2];
  const float* Wkvh = (const float*)d_in[3];
  const float* Wg   = (const float*)d_in[4];
  const float* Wout = (const float*)d_in[5];
  float* out = (float*)d_out;

  char* ws = (char*)d_ws;
  size_t off = 0;
  auto alloc = [&](size_t bytes) -> void* {
    void* p = ws + off;
    off += (bytes + 255) & ~(size_t)255;
    return p;
  };
  unsigned short* x_bf    = (unsigned short*)alloc(4096ull * 2048 * 2);
  unsigned short* wq_bf   = (unsigned short*)alloc(2048ull * 2048 * 2);
  unsigned short* wout_bf = (unsigned short*)alloc(2048ull * 2048 * 2);
  unsigned short* wsm_bf  = (unsigned short*)alloc(384ull * 2048 * 2);
  unsigned short* q_r     = (unsigned short*)alloc(4096ull * 2048 * 2);
  unsigned short* k_r     = (unsigned short*)alloc(4096ull * 2048 * 2);
  unsigned short* v_r     = (unsigned short*)alloc(4096ull * 2048 * 2);
  unsigned short* o_bf    = (unsigned short*)alloc(4096ull * 2048 * 2);
  float* small_out        = (float*)alloc(4096ull * 384 * 4);
  float* g_f              = (float*)alloc(4096ull * 32 * 4);
  float* khvh             = (float*)alloc(4096ull * 32 * 4);
  float2* cs              = (float2*)alloc(2048ull * 64 * 8);

  cast_f32_bf16<<<4096, 256, 0, stream>>>(x, x_bf, 4096 * 2048);
  cast_f32_bf16<<<2048, 256, 0, stream>>>(Wq, wq_bf, 2048 * 2048);
  cast_f32_bf16<<<2048, 256, 0, stream>>>(Wout, wout_bf, 2048 * 2048);
  build_wsmall<<<384, 256, 0, stream>>>(Wkv, Wkvh, wsm_bf);
  rope_table<<<512, 256, 0, stream>>>(cs);
  gproj<<<512, 256, 0, stream>>>(x, Wg, g_f);
  gemm_bt<0><<<dim3(3, 32), 256, 0, stream>>>(x_bf, wsm_bf, small_out, nullptr, 2048, 384);
  gemm_bt<2><<<dim3(16, 32), 256, 0, stream>>>(x_bf, wq_bf, nullptr, q_r, 2048, 2048);
  scan_kernel<<<64, 256, 0, stream>>>(g_f, small_out, khvh);
  rope_q<<<16384, 256, 0, stream>>>(q_r, cs);
  build_kv<<<4096, 256, 0, stream>>>(small_out, khvh, cs, k_r, v_r);
  flash_attn<<<dim3(32, 32), 256, 0, stream>>>(q_r, k_r, v_r, o_bf);
  gemm_bt<0><<<dim3(16, 32), 256, 0, stream>>>(o_bf, wout_bf, out, nullptr, 2048, 2048);
}

// Round 2
// 530.756 us; speedup vs baseline: 1.3848x; 1.3848x over previous
//
#include <hip/hip_runtime.h>
#include <hip/hip_bf16.h>
#include <math.h>

// ---------- types ----------
typedef __attribute__((ext_vector_type(8))) short bf16x8;
typedef __attribute__((ext_vector_type(4))) float f32x4;

#define MFMA16(a, b, c) __builtin_amdgcn_mfma_f32_16x16x32_bf16((a), (b), (c), 0, 0, 0)

static __device__ __forceinline__ unsigned short f2bf(float f) {
  __hip_bfloat16 h = __float2bfloat16(f);
  unsigned short u;
  __builtin_memcpy(&u, &h, 2);
  return u;
}
static __device__ __forceinline__ float bf2f(unsigned short u) {
  unsigned int x = ((unsigned int)u) << 16;
  float f;
  __builtin_memcpy(&f, &x, 4);
  return f;
}

// ---------- cast fp32 -> bf16 (vectorized) ----------
__global__ void cast_f32_bf16(const float* __restrict__ src, unsigned short* __restrict__ dst, int n) {
  int i = (blockIdx.x * 256 + threadIdx.x) * 8;
  if (i >= n) return;
  float4 a = *(const float4*)(src + i);
  float4 b = *(const float4*)(src + i + 4);
  union { unsigned short u[8]; bf16x8 v; } o;
  o.u[0] = f2bf(a.x); o.u[1] = f2bf(a.y); o.u[2] = f2bf(a.z); o.u[3] = f2bf(a.w);
  o.u[4] = f2bf(b.x); o.u[5] = f2bf(b.y); o.u[6] = f2bf(b.z); o.u[7] = f2bf(b.w);
  *(bf16x8*)(dst + i) = o.v;
}

// ---------- Wsmall = [Wkv(256) ; Wkvh(32) ; zeros(96)]  (384 x 2048, bf16) ----------
__global__ void build_wsmall(const float* __restrict__ Wkv, const float* __restrict__ Wkvh,
                             unsigned short* __restrict__ dst) {
  int row = blockIdx.x;           // 0..383
  int c = threadIdx.x * 8;        // 0..2040
  const float* src = nullptr;
  if (row < 256) src = Wkv + (size_t)row * 2048;
  else if (row < 288) src = Wkvh + (size_t)(row - 256) * 2048;
  union { unsigned short u[8]; bf16x8 v; } o;
  if (src) {
    float4 a = *(const float4*)(src + c);
    float4 b = *(const float4*)(src + c + 4);
    o.u[0] = f2bf(a.x); o.u[1] = f2bf(a.y); o.u[2] = f2bf(a.z); o.u[3] = f2bf(a.w);
    o.u[4] = f2bf(b.x); o.u[5] = f2bf(b.y); o.u[6] = f2bf(b.z); o.u[7] = f2bf(b.w);
  } else {
    for (int j = 0; j < 8; j++) o.u[j] = 0;
  }
  *(bf16x8*)(dst + (size_t)row * 2048 + c) = o.v;
}

// ---------- rope cos/sin table: (n, f) f<64 ----------
__global__ void rope_table(float2* __restrict__ cs) {
  int i = blockIdx.x * 256 + threadIdx.x;  // 2048*64
  int f = i & 63, n = i >> 6;
  float inv = powf(10000.0f, -(float)(2 * f) / 128.0f);
  float ang = (float)n * inv;
  cs[i] = make_float2(cosf(ang), sinf(ang));
}

// ---------- g = x @ Wg^T in fp32 (precision-critical) ----------
__global__ __launch_bounds__(256) void gproj(const float* __restrict__ x, const float* __restrict__ Wg,
                                             float* __restrict__ g) {
  int tid = blockIdx.x * 256 + threadIdx.x;  // 4096*32
  int tok = tid >> 5, oc = tid & 31;
  const float* xr = x + (size_t)tok * 2048;
  const float* wr = Wg + (size_t)oc * 2048;
  float acc = 0.f;
  for (int k = 0; k < 2048; k += 4) {
    float4 a = *(const float4*)(xr + k);
    float4 w = *(const float4*)(wr + k);
    acc += a.x * w.x + a.y * w.y + a.z * w.z + a.w * w.w;
  }
  g[(size_t)tok * 32 + oc] = acc;
}

// ---------- gated double cumsum scan, per (b, ch) ----------
__global__ __launch_bounds__(256) void scan_kernel(const float* __restrict__ g,
                                                   const float* __restrict__ small_out,
                                                   float* __restrict__ khvh) {
  int b = blockIdx.x >> 5, ch = blockIdx.x & 31;
  int t = threadIdx.x;
  __shared__ float part[256];
  int base_tok = b * 2048;
  float lsg[8];
  float run = 0.f;
#pragma unroll
  for (int j = 0; j < 8; j++) {
    int n = t * 8 + j;
    float gv = g[(size_t)(base_tok + n) * 32 + ch];
    float ls = (gv >= 0.f) ? -log1pf(expf(-gv)) : gv - log1pf(expf(gv));
    run += ls;
    lsg[j] = run;
  }
  part[t] = run;
  __syncthreads();
  for (int off = 1; off < 256; off <<= 1) {
    float v = (t >= off) ? part[t - off] : 0.f;
    __syncthreads();
    part[t] += v;
    __syncthreads();
  }
  float base = (t > 0) ? part[t - 1] : 0.f;
  __syncthreads();
  float term[8];
  float run2 = 0.f;
#pragma unroll
  for (int j = 0; j < 8; j++) {
    int n = t * 8 + j;
    float kvh = small_out[(size_t)(base_tok + n) * 384 + 256 + ch];
    float lf = base + (j > 0 ? lsg[j - 1] : 0.f);
    run2 += kvh * expf(lf);
    term[j] = run2;
  }
  part[t] = run2;
  __syncthreads();
  for (int off = 1; off < 256; off <<= 1) {
    float v = (t >= off) ? part[t - off] : 0.f;
    __syncthreads();
    part[t] += v;
    __syncthreads();
  }
  float base2 = (t > 0) ? part[t - 1] : 0.f;
#pragma unroll
  for (int j = 0; j < 8; j++) {
    int n = t * 8 + j;
    khvh[(size_t)(base_tok + n) * 32 + ch] = base2 + term[j];
  }
}

// ---------- rope q in place, q_r layout (b,h,n,d) ----------
__global__ void rope_q(unsigned short* __restrict__ q_r, const float2* __restrict__ cs) {
  int i = blockIdx.x * 256 + threadIdx.x;  // 32*2048*64
  int f = i & 63;
  int n = (i >> 6) & 2047;
  int bh = i >> 17;
  unsigned short* p = q_r + ((size_t)bh * 2048 + n) * 128;
  float t1 = bf2f(p[f]), t2 = bf2f(p[f + 64]);
  float2 c = cs[(n << 6) + f];
  p[f] = f2bf(t1 * c.x - t2 * c.y);
  p[f + 64] = f2bf(t2 * c.x + t1 * c.y);
}

// ---------- build k_r, v_r (b,h,n,d) = rope(kp)*kh , vp*vh ----------
__global__ __launch_bounds__(256) void build_kv(const float* __restrict__ small_out,
                                                const float* __restrict__ khvh,
                                                const float2* __restrict__ cs,
                                                unsigned short* __restrict__ k_r,
                                                unsigned short* __restrict__ v_r) {
  int tok = blockIdx.x;
  int b = tok >> 11, n = tok & 2047;
  __shared__ float kpr[128], vps[128], khs[16], vhs[16];
  int t = threadIdx.x;
  const float* so = small_out + (size_t)tok * 384;
  if (t < 64) {
    float k1 = so[t], k2 = so[t + 64];
    float2 c = cs[(n << 6) + t];
    kpr[t] = k1 * c.x - k2 * c.y;
    kpr[t + 64] = k2 * c.x + k1 * c.y;
  } else if (t < 192) {
    int d = t - 64;
    vps[d] = so[128 + d];
  } else if (t < 224) {
    int ch = t - 192;
    float v = khvh[(size_t)tok * 32 + ch];
    if (ch < 16) khs[ch] = v; else vhs[ch - 16] = v;
  }
  __syncthreads();
#pragma unroll
  for (int i = 0; i < 8; i++) {
    int idx = i * 256 + t;
    int h = idx >> 7, d = idx & 127;
    size_t o = (((size_t)b * 16 + h) * 2048 + n) * 128 + d;
    k_r[o] = f2bf(kpr[d] * khs[h]);
    v_r[o] = f2bf(vps[d] * vhs[h]);
  }
}

// ---------- v_t (b,h,d,n) <- v_r (b,h,n,d), LDS-tiled transpose ----------
__global__ __launch_bounds__(256) void transpose_v(const unsigned short* __restrict__ v_r,
                                                   unsigned short* __restrict__ v_t) {
  int nt = blockIdx.x;   // 64-token tile
  int bh = blockIdx.y;
  __shared__ unsigned short Ts[64 * 136];
  int tid = threadIdx.x;
  const unsigned short* src = v_r + ((size_t)bh * 2048 + nt * 64) * 128;
#pragma unroll
  for (int c = 0; c < 4; c++) {
    int g = c * 256 + tid;
    int r = g >> 4, ch = (g & 15) * 8;
    *(bf16x8*)&Ts[r * 136 + ch] = *(const bf16x8*)(src + r * 128 + ch);
  }
  __syncthreads();
#pragma unroll
  for (int c = 0; c < 4; c++) {
    int g = c * 256 + tid;
    int d = g >> 3, nc = (g & 7) * 8;
    union { unsigned short u[8]; bf16x8 v; } o;
#pragma unroll
    for (int j = 0; j < 8; j++) o.u[j] = Ts[(nc + j) * 136 + d];
    *(bf16x8*)(v_t + ((size_t)bh * 128 + d) * 2048 + nt * 64 + nc) = o.v;
  }
}

// ---------- m97-style NT GEMM ----------
template <int MODE>
__global__ __launch_bounds__(256) void gemm_bt(const unsigned short* __restrict__ A,
                                               const unsigned short* __restrict__ B,
                                               float* __restrict__ Cf,
                                               unsigned short* __restrict__ Cb,
                                               int K, int ldc) {
  __shared__ unsigned short As[128 * 32];
  __shared__ unsigned short Bs[128 * 32];
  int tid = threadIdx.x;
  int wave = tid >> 6, lane = tid & 63, l15 = lane & 15, lg = lane >> 4;
  int wr = wave >> 1, wc = wave & 1;
  int row0 = blockIdx.y * 128, col0 = blockIdx.x * 128;
  f32x4 acc[4][4];
#pragma unroll
  for (int m = 0; m < 4; m++)
#pragma unroll
    for (int n = 0; n < 4; n++) acc[m][n] = (f32x4){0.f, 0.f, 0.f, 0.f};

  for (int k0 = 0; k0 < K; k0 += 32) {
#pragma unroll
    for (int c = 0; c < 2; c++) {
      int chunk = c * 256 + tid;
      int r = chunk >> 2, kk = (chunk & 3) * 8;
      __builtin_amdgcn_global_load_lds(
          (const __attribute__((address_space(1))) void*)(A + (size_t)(row0 + r) * K + k0 + kk),
          (__attribute__((address_space(3))) void*)(As + ((size_t)c * 256 + wave * 64) * 8), 16, 0, 0);
      __builtin_amdgcn_global_load_lds(
          (const __attribute__((address_space(1))) void*)(B + (size_t)(col0 + r) * K + k0 + kk),
          (__attribute__((address_space(3))) void*)(Bs + ((size_t)c * 256 + wave * 64) * 8), 16, 0, 0);
    }
    __syncthreads();
    bf16x8 af[4], bfr[4];
#pragma unroll
    for (int m = 0; m < 4; m++) af[m] = *(const bf16x8*)&As[(wr * 64 + m * 16 + l15) * 32 + lg * 8];
#pragma unroll
    for (int n = 0; n < 4; n++) bfr[n] = *(const bf16x8*)&Bs[(wc * 64 + n * 16 + l15) * 32 + lg * 8];
#pragma unroll
    for (int m = 0; m < 4; m++)
#pragma unroll
      for (int n = 0; n < 4; n++) acc[m][n] = MFMA16(af[m], bfr[n], acc[m][n]);
    __syncthreads();
  }
#pragma unroll
  for (int m = 0; m < 4; m++) {
    int row_b = row0 + wr * 64 + m * 16 + lg * 4;
#pragma unroll
    for (int n = 0; n < 4; n++) {
      int col = col0 + wc * 64 + n * 16 + l15;
#pragma unroll
      for (int j = 0; j < 4; j++) {
        int row = row_b + j;
        if (MODE == 0) {
          Cf[(size_t)row * ldc + col] = acc[m][n][j];
        } else {
          int b = row >> 11, nn = row & 2047, h = col >> 7, d = col & 127;
          Cb[(((size_t)b * 16 + h) * 2048 + nn) * 128 + d] = f2bf(acc[m][n][j]);
        }
      }
    }
  }
}

// ---------- flash attention v2: K/VT via global_load_lds + XOR swizzle ----------
__global__ __launch_bounds__(256) void flash_attn(const unsigned short* __restrict__ q_r,
                                                  const unsigned short* __restrict__ k_r,
                                                  const unsigned short* __restrict__ v_t,
                                                  unsigned short* __restrict__ o) {
  int qt = blockIdx.x, bh = blockIdx.y;
  const unsigned short* Qg = q_r + ((size_t)bh * 2048 + qt * 64) * 128;
  const unsigned short* Kg = k_r + (size_t)bh * 2048 * 128;
  const unsigned short* Vtg = v_t + (size_t)bh * 128 * 2048;
  __shared__ unsigned short Ks[64 * 128];    // linear, XOR-swizzled content
  __shared__ unsigned short VTs[128 * 64];   // [d][kv], linear, XOR-swizzled content
  __shared__ unsigned short Ps[4][16 * 72];
  int tid = threadIdx.x, wave = tid >> 6, lane = tid & 63, l15 = lane & 15, lg = lane >> 4;
  int sw = (l15 & 7) * 8;  // fragment-read XOR (shorts)

  // Q fragments direct from global (coalesced 16B per lane)
  bf16x8 qf[4];
#pragma unroll
  for (int kk = 0; kk < 4; kk++)
    qf[kk] = *(const bf16x8*)(Qg + (wave * 16 + l15) * 128 + kk * 32 + lg * 8);

  float m_r[4], l_r[4];
  f32x4 oacc[8];
#pragma unroll
  for (int j = 0; j < 4; j++) { m_r[j] = -INFINITY; l_r[j] = 0.f; }
#pragma unroll
  for (int db = 0; db < 8; db++) oacc[db] = (f32x4){0.f, 0.f, 0.f, 0.f};

  int qrow0 = qt * 64 + wave * 16 + lg * 4;
  const float scale = 0.08838834764831845f;  // 1/sqrt(128)

  for (int kt = 0; kt <= qt; ++kt) {
    // stage K tile: 64 rows x 128 shorts = 1024 granules of 16B
    // stage VT tile: 128 rows x 64 shorts = 1024 granules
    // source granule pre-swizzled so LDS-linear + swizzled-read is an involution
#pragma unroll
    for (int c = 0; c < 4; c++) {
      int s = c * 256 + tid;
      int kr = s >> 4, kc = ((s & 15) ^ (kr & 7)) * 8;
      __builtin_amdgcn_global_load_lds(
          (const __attribute__((address_space(1))) void*)(Kg + (size_t)(kt * 64 + kr) * 128 + kc),
          (__attribute__((address_space(3))) void*)(Ks + (c * 256 + wave * 64) * 8), 16, 0, 0);
      int vr = s >> 3, vc = ((s & 7) ^ (vr & 7)) * 8;
      __builtin_amdgcn_global_load_lds(
          (const __attribute__((address_space(1))) void*)(Vtg + (size_t)vr * 2048 + kt * 64 + vc),
          (__attribute__((address_space(3))) void*)(VTs + (c * 256 + wave * 64) * 8), 16, 0, 0);
    }
    __syncthreads();

    f32x4 s[4];
#pragma unroll
    for (int cb = 0; cb < 4; cb++) s[cb] = (f32x4){0.f, 0.f, 0.f, 0.f};
#pragma unroll
    for (int kk = 0; kk < 4; kk++) {
#pragma unroll
      for (int cb = 0; cb < 4; cb++) {
        bf16x8 kf = *(const bf16x8*)&Ks[(cb * 16 + l15) * 128 + ((kk * 32 + lg * 8) ^ sw)];
        s[cb] = MFMA16(qf[kk], kf, s[cb]);
      }
    }
    float pm[4] = {-INFINITY, -INFINITY, -INFINITY, -INFINITY};
    if (kt == qt) {
#pragma unroll
      for (int cb = 0; cb < 4; cb++) {
        int col = kt * 64 + cb * 16 + l15;
#pragma unroll
        for (int j = 0; j < 4; j++) {
          float v = s[cb][j] * scale;
          if (col > qrow0 + j) v = -INFINITY;
          s[cb][j] = v;
          pm[j] = fmaxf(pm[j], v);
        }
      }
    } else {
#pragma unroll
      for (int cb = 0; cb < 4; cb++)
#pragma unroll
        for (int j = 0; j < 4; j++) {
          float v = s[cb][j] * scale;
          s[cb][j] = v;
          pm[j] = fmaxf(pm[j], v);
        }
    }
#pragma unroll
    for (int off = 1; off < 16; off <<= 1) {
#pragma unroll
      for (int j = 0; j < 4; j++) pm[j] = fmaxf(pm[j], __shfl_xor(pm[j], off));
    }
    float corr[4], rs[4];
#pragma unroll
    for (int j = 0; j < 4; j++) {
      float mn = fmaxf(m_r[j], pm[j]);
      corr[j] = __expf(m_r[j] - mn);
      m_r[j] = mn;
      rs[j] = 0.f;
    }
    float p[4][4];
#pragma unroll
    for (int cb = 0; cb < 4; cb++)
#pragma unroll
      for (int j = 0; j < 4; j++) {
        float pv = __expf(s[cb][j] - m_r[j]);
        p[cb][j] = pv;
        rs[j] += pv;
      }
#pragma unroll
    for (int off = 1; off < 16; off <<= 1) {
#pragma unroll
      for (int j = 0; j < 4; j++) rs[j] += __shfl_xor(rs[j], off);
    }
#pragma unroll
    for (int j = 0; j < 4; j++) l_r[j] = l_r[j] * corr[j] + rs[j];
#pragma unroll
    for (int db = 0; db < 8; db++) {
      f32x4 t = oacc[db];
#pragma unroll
      for (int j = 0; j < 4; j++) t[j] *= corr[j];
      oacc[db] = t;
    }
#pragma unroll
    for (int cb = 0; cb < 4; cb++)
#pragma unroll
      for (int j = 0; j < 4; j++) Ps[wave][(lg * 4 + j) * 72 + cb * 16 + l15] = f2bf(p[cb][j]);
    __syncthreads();
#pragma unroll
    for (int kc = 0; kc < 2; kc++) {
      bf16x8 pa = *(const bf16x8*)&Ps[wave][l15 * 72 + kc * 32 + lg * 8];
#pragma unroll
      for (int db = 0; db < 8; db++) {
        bf16x8 vb = *(const bf16x8*)&VTs[(db * 16 + l15) * 64 + ((kc * 32 + lg * 8) ^ sw)];
        oacc[db] = MFMA16(pa, vb, oacc[db]);
      }
    }
    __syncthreads();
  }
  int b = bh >> 4, h = bh & 15;
#pragma unroll
  for (int db = 0; db < 8; db++) {
    int d = db * 16 + l15;
#pragma unroll
    for (int j = 0; j < 4; j++) {
      int row = qrow0 + j;
      float val = oacc[db][j] / l_r[j];
      o[((size_t)(b * 2048 + row)) * 2048 + h * 128 + d] = f2bf(val);
    }
  }
}

// ---------- host launch ----------
extern "C" void kernel_launch(void* const* d_in, const int* in_sizes, int n_in,
                              void* d_out, int out_size, void* d_ws, size_t ws_size,
                              hipStream_t stream) {
  (void)in_sizes; (void)n_in; (void)out_size; (void)ws_size;
  const float* x    = (const float*)d_in[0];
  const float* Wq   = (const float*)d_in[1];
  const float* Wkv  = (const float*)d_in[2];
  const float* Wkvh = (const float*)d_in[3];
  const float* Wg   = (const float*)d_in[4];
  const float* Wout = (const float*)d_in[5];
  float* out = (float*)d_out;

  char* ws = (char*)d_ws;
  size_t off = 0;
  auto alloc = [&](size_t bytes) -> void* {
    void* p = ws + off;
    off += (bytes + 255) & ~(size_t)255;
    return p;
  };
  unsigned short* x_bf    = (unsigned short*)alloc(4096ull * 2048 * 2);
  unsigned short* wq_bf   = (unsigned short*)alloc(2048ull * 2048 * 2);
  unsigned short* wout_bf = (unsigned short*)alloc(2048ull * 2048 * 2);
  unsigned short* wsm_bf  = (unsigned short*)alloc(384ull * 2048 * 2);
  unsigned short* q_r     = (unsigned short*)alloc(4096ull * 2048 * 2);
  unsigned short* k_r     = (unsigned short*)alloc(4096ull * 2048 * 2);
  unsigned short* v_r     = (unsigned short*)alloc(4096ull * 2048 * 2);
  unsigned short* o_bf    = (unsigned short*)alloc(4096ull * 2048 * 2);
  float* small_out        = (float*)alloc(4096ull * 384 * 4);
  float* g_f              = (float*)alloc(4096ull * 32 * 4);
  float* khvh             = (float*)alloc(4096ull * 32 * 4);
  float2* cs              = (float2*)alloc(2048ull * 64 * 8);
  // v_t aliases x_bf: x_bf is dead after the q/small GEMMs, transpose_v runs later
  unsigned short* v_t     = x_bf;

  cast_f32_bf16<<<4096, 256, 0, stream>>>(x, x_bf, 4096 * 2048);
  cast_f32_bf16<<<2048, 256, 0, stream>>>(Wq, wq_bf, 2048 * 2048);
  cast_f32_bf16<<<2048, 256, 0, stream>>>(Wout, wout_bf, 2048 * 2048);
  build_wsmall<<<384, 256, 0, stream>>>(Wkv, Wkvh, wsm_bf);
  rope_table<<<512, 256, 0, stream>>>(cs);
  gproj<<<512, 256, 0, stream>>>(x, Wg, g_f);
  gemm_bt<0><<<dim3(3, 32), 256, 0, stream>>>(x_bf, wsm_bf, small_out, nullptr, 2048, 384);
  gemm_bt<2><<<dim3(16, 32), 256, 0, stream>>>(x_bf, wq_bf, nullptr, q_r, 2048, 2048);
  scan_kernel<<<64, 256, 0, stream>>>(g_f, small_out, khvh);
  rope_q<<<16384, 256, 0, stream>>>(q_r, cs);
  build_kv<<<4096, 256, 0, stream>>>(small_out, khvh, cs, k_r, v_r);
  transpose_v<<<dim3(32, 32), 256, 0, stream>>>(v_r, v_t);
  flash_attn<<<dim3(32, 32), 256, 0, stream>>>(q_r, k_r, v_t, o_bf);
  gemm_bt<0><<<dim3(16, 32), 256, 0, stream>>>(o_bf, wout_bf, out, nullptr, 2048, 2048);
}